// Round 1
// baseline (905.901 us; speedup 1.0000x reference)
//
#include <hip/hip_runtime.h>
#include <cstdint>
#include <cstddef>

typedef unsigned short u16;
typedef unsigned int u32;
typedef short bfrag __attribute__((ext_vector_type(8)));   // 8 bf16 bit-patterns (4 VGPR)
typedef __bf16 yfrag __attribute__((ext_vector_type(8)));  // alt spelling for the builtin
typedef float f4 __attribute__((ext_vector_type(4)));

// ---------- scalar bf16 helpers (RNE) ----------
__device__ __forceinline__ u16 f2bs(float f) {
  union { float f; u32 u; } x; x.f = f;
  u32 r = x.u + 0x7fffu + ((x.u >> 16) & 1u);
  return (u16)(r >> 16);
}
__device__ __forceinline__ float bs2f(u16 s) {
  union { u32 u; float f; } x; x.u = ((u32)s) << 16;
  return x.f;
}

// ---------- MFMA wrapper: robust to either builtin operand type ----------
// If the builtin takes short8, overload (int) wins. If it takes __bf16x8,
// overload (int) SFINAEs out and (long) bit_casts. Only the chosen body is
// instantiated.
template <typename T>
__device__ __forceinline__ auto mfma_sel(T a, T b, f4 c, int)
    -> decltype(__builtin_amdgcn_mfma_f32_16x16x32_bf16(a, b, c, 0, 0, 0)) {
  return __builtin_amdgcn_mfma_f32_16x16x32_bf16(a, b, c, 0, 0, 0);
}
template <typename T>
__device__ __forceinline__ f4 mfma_sel(T a, T b, f4 c, long) {
  yfrag ya = __builtin_bit_cast(yfrag, a);
  yfrag yb = __builtin_bit_cast(yfrag, b);
  return __builtin_amdgcn_mfma_f32_16x16x32_bf16(ya, yb, c, 0, 0, 0);
}
__device__ __forceinline__ f4 MFMA(bfrag a, bfrag b, f4 c) {
  return mfma_sel(a, b, c, 0);
}

// ---------- async global->LDS, 16B per lane, wave-uniform LDS base ----------
__device__ __forceinline__ void gl2lds16(const u16* g, u16* l) {
  __builtin_amdgcn_global_load_lds(
      (__attribute__((address_space(1))) void*)(g),
      (__attribute__((address_space(3))) void*)(l), 16, 0, 0);
}

// =====================================================================
// fp32 -> bf16 elementwise convert (8 elems/thread)
// =====================================================================
__global__ __launch_bounds__(256) void cvt_bf16(const float* __restrict__ src,
                                                u16* __restrict__ dst, int n8) {
  int i = blockIdx.x * 256 + threadIdx.x;
  if (i >= n8) return;
  const float4* s4 = (const float4*)src;
  float4 a = s4[(size_t)i * 2];
  float4 b = s4[(size_t)i * 2 + 1];
  uint4 o;
  o.x = (u32)f2bs(a.x) | ((u32)f2bs(a.y) << 16);
  o.y = (u32)f2bs(a.z) | ((u32)f2bs(a.w) << 16);
  o.z = (u32)f2bs(b.x) | ((u32)f2bs(b.y) << 16);
  o.w = (u32)f2bs(b.z) | ((u32)f2bs(b.w) << 16);
  ((uint4*)dst)[i] = o;
}

// =====================================================================
// transpose 1536x1536 fp32 -> bf16, 6 weights in one launch (z picks)
// dst[n][k] = src[k][n]
// =====================================================================
__global__ __launch_bounds__(256) void transpose6(
    const float* s0, const float* s1, const float* s2, const float* s3,
    const float* s4, const float* s5, u16* d0, u16* d1, u16* d2, u16* d3,
    u16* d4, u16* d5) {
  const float* src; u16* dst;
  switch (blockIdx.z) {
    case 0: src = s0; dst = d0; break;
    case 1: src = s1; dst = d1; break;
    case 2: src = s2; dst = d2; break;
    case 3: src = s3; dst = d3; break;
    case 4: src = s4; dst = d4; break;
    default: src = s5; dst = d5; break;
  }
  __shared__ float tile[32][33];
  int tx = threadIdx.x, ty = threadIdx.y;
  int bx = blockIdx.x * 32, by = blockIdx.y * 32;
#pragma unroll
  for (int j = 0; j < 4; j++)
    tile[ty + j * 8][tx] = src[(size_t)(by + ty + j * 8) * 1536 + bx + tx];
  __syncthreads();
#pragma unroll
  for (int j = 0; j < 4; j++)
    dst[(size_t)(bx + ty + j * 8) * 1536 + by + tx] = f2bs(tile[tx][ty + j * 8]);
}

// =====================================================================
// bf16 GEMM, C = A(MxK) * Bt(NxK)^T + bias, K=N=1536, tile 128x128, BK=32.
// m97 structure: global_load_lds width-16 staging, 2-barrier K-loop.
// epi: 0 = bf16 C[m][n], 1 = bf16 C^T (dst[n*ldT+m]), 2 = fp32 C[m][n]
// =====================================================================
__global__ __launch_bounds__(256) void gemm_bt(
    const u16* __restrict__ A, const u16* __restrict__ Bt,
    const float* __restrict__ bias, void* __restrict__ outp, int Mreal,
    int ldT, int epi) {
  __shared__ u16 As[128 * 32];
  __shared__ u16 Bs[128 * 32];
  const int tid = threadIdx.x;
  const int w = tid >> 6, lane = tid & 63;
  const int quad = lane >> 4, l15 = lane & 15;
  const int m0 = blockIdx.x * 128, n0 = blockIdx.y * 128;
  const int wm = (w >> 1) * 64, wn = (w & 1) * 64;

  f4 acc[4][4];
#pragma unroll
  for (int i = 0; i < 4; i++)
#pragma unroll
    for (int j = 0; j < 4; j++) acc[i][j] = f4{0.f, 0.f, 0.f, 0.f};

  // staging chunks: chunk = (w*2+call)*64 + lane; row = chunk>>2, seg = chunk&3
  const int c0 = w * 128 + lane;
  const int c1 = c0 + 64;
  const int ar0 = c0 >> 2, as0 = (c0 & 3) * 8;
  const int ar1 = c1 >> 2, as1 = (c1 & 3) * 8;
  const u16* Ab = A + (size_t)m0 * 1536;
  const u16* Bb = Bt + (size_t)n0 * 1536;
  u16* ldsA0 = As + (w * 2 + 0) * 512;
  u16* ldsA1 = As + (w * 2 + 1) * 512;
  u16* ldsB0 = Bs + (w * 2 + 0) * 512;
  u16* ldsB1 = Bs + (w * 2 + 1) * 512;

  for (int kt = 0; kt < 48; ++kt) {
    const int k0 = kt * 32;
    gl2lds16(Ab + (size_t)ar0 * 1536 + k0 + as0, ldsA0);
    gl2lds16(Ab + (size_t)ar1 * 1536 + k0 + as1, ldsA1);
    gl2lds16(Bb + (size_t)ar0 * 1536 + k0 + as0, ldsB0);
    gl2lds16(Bb + (size_t)ar1 * 1536 + k0 + as1, ldsB1);
    __syncthreads();  // drains vmcnt -> staged data visible
    bfrag af[4], bfr[4];
#pragma unroll
    for (int i = 0; i < 4; i++)
      af[i] = *(const bfrag*)(As + (wm + i * 16 + l15) * 32 + quad * 8);
#pragma unroll
    for (int j = 0; j < 4; j++)
      bfr[j] = *(const bfrag*)(Bs + (wn + j * 16 + l15) * 32 + quad * 8);
#pragma unroll
    for (int i = 0; i < 4; i++)
#pragma unroll
      for (int j = 0; j < 4; j++) acc[i][j] = MFMA(af[i], bfr[j], acc[i][j]);
    __syncthreads();  // all waves done reading before next overwrite
  }

  float bcol[4];
#pragma unroll
  for (int j = 0; j < 4; j++) bcol[j] = bias[n0 + wn + j * 16 + l15];

  if (epi == 1) {
    u16* dst = (u16*)outp;
#pragma unroll
    for (int i = 0; i < 4; i++)
#pragma unroll
      for (int r = 0; r < 4; r++) {
        int row = m0 + wm + i * 16 + quad * 4 + r;
        if (row < Mreal) {
#pragma unroll
          for (int j = 0; j < 4; j++) {
            int col = n0 + wn + j * 16 + l15;
            dst[(size_t)col * ldT + row] = f2bs(acc[i][j][r] + bcol[j]);
          }
        }
      }
  } else if (epi == 0) {
    u16* dst = (u16*)outp;
#pragma unroll
    for (int i = 0; i < 4; i++)
#pragma unroll
      for (int r = 0; r < 4; r++) {
        int row = m0 + wm + i * 16 + quad * 4 + r;
        if (row < Mreal) {
#pragma unroll
          for (int j = 0; j < 4; j++) {
            int col = n0 + wn + j * 16 + l15;
            dst[(size_t)row * 1536 + col] = f2bs(acc[i][j][r] + bcol[j]);
          }
        }
      }
  } else {
    float* dst = (float*)outp;
#pragma unroll
    for (int i = 0; i < 4; i++)
#pragma unroll
      for (int r = 0; r < 4; r++) {
        int row = m0 + wm + i * 16 + quad * 4 + r;
        if (row < Mreal) {
#pragma unroll
          for (int j = 0; j < 4; j++) {
            int col = n0 + wn + j * 16 + l15;
            dst[(size_t)row * 1536 + col] = acc[i][j][r] + bcol[j];
          }
        }
      }
  }
}

// =====================================================================
// in-place RMSNorm over 1536 cols, bf16 buf, fp32 gain. One block per row.
// =====================================================================
__global__ __launch_bounds__(256) void rmsnorm_kernel(u16* __restrict__ buf,
                                                      const float* __restrict__ g) {
  const int row = blockIdx.x;
  const int tid = threadIdx.x;
  u16* p = buf + (size_t)row * 1536;
  float v[6];
  float ss = 0.f;
#pragma unroll
  for (int j = 0; j < 6; j++) {
    v[j] = bs2f(p[tid + j * 256]);
    ss += v[j] * v[j];
  }
#pragma unroll
  for (int off = 32; off; off >>= 1) ss += __shfl_xor(ss, off);
  __shared__ float red[4];
  if ((tid & 63) == 0) red[tid >> 6] = ss;
  __syncthreads();
  ss = red[0] + red[1] + red[2] + red[3];
  const float sc = rsqrtf(ss * (1.0f / 1536.0f) + 1e-6f);
#pragma unroll
  for (int j = 0; j < 6; j++)
    p[tid + j * 256] = f2bs(v[j] * sc * g[tid + j * 256]);
}

// =====================================================================
// Fused dual-segment attention. Block = (64 q-rows, 1 head), 4 waves.
// Wave owns 16 q-rows; online softmax over img (257 keys) then txt (512),
// outputs summed; y[m][h*128+d] bf16.
// Layouts: q/k row-major (tok,1536); vT (12,128,Lk) with ld 264/512.
// =====================================================================
#define ATTN_SCALE 0.08838834764831845f
__global__ __launch_bounds__(256) void attn_kernel(
    const u16* __restrict__ q, const u16* __restrict__ ktxt,
    const u16* __restrict__ kimg, const u16* __restrict__ vttxt,
    const u16* __restrict__ vtimg, u16* __restrict__ y) {
  __shared__ u16 Qs[64 * 136];   // padded stride 136
  __shared__ u16 Ks[32 * 136];
  __shared__ u16 Vs[128 * 40];   // V^T chunk, padded stride 40
  __shared__ u16 Ps[4 * 16 * 40]; // per-wave P tile, padded stride 40
  const int tid = threadIdx.x;
  const int w = tid >> 6, lane = tid & 63;
  const int quad = lane >> 4, l15 = lane & 15;
  const int h = blockIdx.y;
  const int m0 = blockIdx.x * 64;

  // stage Q tile (64x128)
#pragma unroll
  for (int p = 0; p < 4; p++) {
    int n = p * 256 + tid;
    int row = n >> 4, sg = (n & 15) * 8;
    *(uint4*)(Qs + row * 136 + sg) =
        *(const uint4*)(q + (size_t)(m0 + row) * 1536 + h * 128 + sg);
  }
  __syncthreads();
  bfrag qf[4];
#pragma unroll
  for (int c = 0; c < 4; c++)
    qf[c] = *(const bfrag*)(Qs + (w * 16 + l15) * 136 + c * 32 + quad * 8);

  f4 res[8];
#pragma unroll
  for (int ft = 0; ft < 8; ft++) res[ft] = f4{0.f, 0.f, 0.f, 0.f};

  for (int seg = 0; seg < 2; seg++) {
    const u16* kp = (seg == 0) ? kimg : ktxt;
    const u16* vp = (seg == 0) ? vtimg : vttxt;
    const int Lk = (seg == 0) ? 257 : 512;
    const int ldv = (seg == 0) ? 264 : 512;
    const int nit = (seg == 0) ? 9 : 16;
    f4 o[8];
#pragma unroll
    for (int ft = 0; ft < 8; ft++) o[ft] = f4{0.f, 0.f, 0.f, 0.f};
    float mr[4] = {-1e30f, -1e30f, -1e30f, -1e30f};
    float lr[4] = {0.f, 0.f, 0.f, 0.f};

    for (int it = 0; it < nit; ++it) {
      const int t0 = it * 32;
      __syncthreads();  // previous K/V chunk fully consumed
#pragma unroll
      for (int p = 0; p < 2; p++) {
        int n = p * 256 + tid;
        // K chunk (32 keys x 128), zero-fill beyond Lk
        int r = n >> 4, sg = (n & 15) * 8;
        uint4 kv = make_uint4(0u, 0u, 0u, 0u);
        if (t0 + r < Lk)
          kv = *(const uint4*)(kp + (size_t)(t0 + r) * 1536 + h * 128 + sg);
        *(uint4*)(Ks + r * 136 + sg) = kv;
        // V^T chunk (128 feats x 32 keys)
        int d = n >> 2, cc = (n & 3) * 8;
        *(uint4*)(Vs + d * 40 + cc) =
            *(const uint4*)(vp + (size_t)(h * 128 + d) * ldv + t0 + cc);
      }
      __syncthreads();

      // S = Q * K^T for 32 keys (two 16-wide n-tiles)
      f4 sA = f4{0.f, 0.f, 0.f, 0.f}, sB = f4{0.f, 0.f, 0.f, 0.f};
#pragma unroll
      for (int c = 0; c < 4; c++) {
        bfrag k0f = *(const bfrag*)(Ks + l15 * 136 + c * 32 + quad * 8);
        bfrag k1f = *(const bfrag*)(Ks + (16 + l15) * 136 + c * 32 + quad * 8);
        sA = MFMA(qf[c], k0f, sA);
        sB = MFMA(qf[c], k1f, sB);
      }
      const bool ok0 = (t0 + l15) < Lk;
      const bool ok1 = (t0 + 16 + l15) < Lk;
      float pa[4], pb[4], al[4];
#pragma unroll
      for (int r = 0; r < 4; r++) {
        float a = ok0 ? sA[r] * ATTN_SCALE : -1e30f;
        float b = ok1 ? sB[r] * ATTN_SCALE : -1e30f;
        float mx = fmaxf(a, b);
#pragma unroll
        for (int off = 1; off < 16; off <<= 1) mx = fmaxf(mx, __shfl_xor(mx, off));
        float mn = fmaxf(mr[r], mx);
        float alv = __expf(mr[r] - mn);
        float p0 = __expf(a - mn);
        float p1 = __expf(b - mn);
        float rs = p0 + p1;
#pragma unroll
        for (int off = 1; off < 16; off <<= 1) rs += __shfl_xor(rs, off);
        lr[r] = lr[r] * alv + rs;
        mr[r] = mn;
        al[r] = alv;
        pa[r] = p0;
        pb[r] = p1;
      }
#pragma unroll
      for (int ft = 0; ft < 8; ft++) {
        o[ft][0] *= al[0]; o[ft][1] *= al[1];
        o[ft][2] *= al[2]; o[ft][3] *= al[3];
      }
      // P: C-layout -> LDS -> A-layout (per-wave region, wave-internal dep)
      u16* Pw = Ps + w * 640;
#pragma unroll
      for (int r = 0; r < 4; r++) {
        Pw[(quad * 4 + r) * 40 + l15] = f2bs(pa[r]);
        Pw[(quad * 4 + r) * 40 + 16 + l15] = f2bs(pb[r]);
      }
      asm volatile("s_waitcnt lgkmcnt(0)" ::: "memory");
      bfrag pf = *(const bfrag*)(Pw + l15 * 40 + quad * 8);
#pragma unroll
      for (int ft = 0; ft < 8; ft++) {
        bfrag vf = *(const bfrag*)(Vs + (ft * 16 + l15) * 40 + quad * 8);
        o[ft] = MFMA(pf, vf, o[ft]);
      }
    }
    float inv[4];
#pragma unroll
    for (int r = 0; r < 4; r++) inv[r] = 1.0f / lr[r];
#pragma unroll
    for (int ft = 0; ft < 8; ft++)
#pragma unroll
      for (int r = 0; r < 4; r++) res[ft][r] += o[ft][r] * inv[r];
  }
  // write y (img+txt attention sum) bf16
#pragma unroll
  for (int ft = 0; ft < 8; ft++)
#pragma unroll
    for (int r = 0; r < 4; r++)
      y[(size_t)(m0 + w * 16 + quad * 4 + r) * 1536 + h * 128 + ft * 16 + l15] =
          f2bs(res[ft][r]);
}

// =====================================================================
extern "C" void kernel_launch(void* const* d_in, const int* in_sizes, int n_in,
                              void* d_out, int out_size, void* d_ws,
                              size_t ws_size, hipStream_t stream) {
  const float* x   = (const float*)d_in[0];
  const float* ctx = (const float*)d_in[1];
  // d_in[2] = context_lens: unused by the reference
  const float* Wq  = (const float*)d_in[3];
  const float* bq  = (const float*)d_in[4];
  const float* Wk  = (const float*)d_in[5];
  const float* bk  = (const float*)d_in[6];
  const float* Wv  = (const float*)d_in[7];
  const float* bv  = (const float*)d_in[8];
  const float* Wak = (const float*)d_in[9];
  const float* bak = (const float*)d_in[10];
  const float* Wav = (const float*)d_in[11];
  const float* bav = (const float*)d_in[12];
  const float* Wo  = (const float*)d_in[13];
  const float* bo  = (const float*)d_in[14];
  const float* gq  = (const float*)d_in[15];
  const float* gk  = (const float*)d_in[16];
  const float* gak = (const float*)d_in[17];
  float* out = (float*)d_out;

  // workspace layout (u16 elements); total ~136 MB
  u16* xbf  = (u16*)d_ws;                 // 16384x1536 bf16 x; reused as y later
  u16* qb   = xbf + 25165824;             // 16384x1536 q
  u16* ctxb = qb + 25165824;              // 769x1536 context bf16
  u16* wqT  = ctxb + 1181184;             // 6 transposed bf16 weights (NxK)
  u16* wkT  = wqT + 2359296;
  u16* wvT  = wkT + 2359296;
  u16* wakT = wvT + 2359296;
  u16* wavT = wakT + 2359296;
  u16* woT  = wavT + 2359296;
  u16* ktxt = woT + 2359296;              // 512x1536
  u16* kimg = ktxt + 786432;              // 257x1536
  u16* vtt  = kimg + 394752;              // V^T txt: 1536x512
  u16* vti  = vtt + 786432;               // V^T img: 1536x264 (+pad)

  // 1) dtype conversions
  cvt_bf16<<<12288, 256, 0, stream>>>(x, xbf, 3145728);
  cvt_bf16<<<577, 256, 0, stream>>>(ctx, ctxb, 147648);
  transpose6<<<dim3(48, 48, 6), dim3(32, 8), 0, stream>>>(
      Wq, Wk, Wv, Wak, Wav, Wo, wqT, wkT, wvT, wakT, wavT, woT);

  // 2) projections (ctx_img = rows [0,257), ctx_txt = rows [257,769))
  gemm_bt<<<dim3(128, 12), 256, 0, stream>>>(xbf, wqT, bq, qb, 16384, 0, 0);
  gemm_bt<<<dim3(4, 12), 256, 0, stream>>>(ctxb + 257 * 1536, wkT, bk, ktxt, 512, 0, 0);
  gemm_bt<<<dim3(3, 12), 256, 0, stream>>>(ctxb, wakT, bak, kimg, 257, 0, 0);
  gemm_bt<<<dim3(4, 12), 256, 0, stream>>>(ctxb + 257 * 1536, wvT, bv, vtt, 512, 512, 1);
  gemm_bt<<<dim3(3, 12), 256, 0, stream>>>(ctxb, wavT, bav, vti, 257, 264, 1);

  // 3) RMSNorms (in-place, full 1536-dim rows)
  rmsnorm_kernel<<<16384, 256, 0, stream>>>(qb, gq);
  rmsnorm_kernel<<<512, 256, 0, stream>>>(ktxt, gk);
  rmsnorm_kernel<<<257, 256, 0, stream>>>(kimg, gak);

  // 4) fused dual attention -> y (reuses xbf region)
  attn_kernel<<<dim3(256, 12), 256, 0, stream>>>(qb, ktxt, kimg, vtt, vti, xbf);

  // 5) output projection, fp32
  gemm_bt<<<dim3(128, 12), 256, 0, stream>>>(xbf, woT, bo, out, 16384, 0, 2);
}